// Round 15
// baseline (1502.245 us; speedup 1.0000x reference)
//
#include <hip/hip_runtime.h>

// MD-RNN on MI355X. B=64, Hd=16, Wd=16, Cd=32, D=64, HID=256.
// hidden[i][j][k] = tanh(x@W_in + up@W1 + left@W2 + prev@W3 + bias)
//
// v16 = BATCH-SPLIT PIPELINING. The batch dim is lattice-independent
// (each row r: hid_r = f(x_r, up_r, left_r, prev_r)), so the 64-row
// problem = 2 independent 32-row lattices. 512 WGs x 256 thr (4 waves,
// 53KB LDS) = exactly 2 WGs/CU (LDS+regcap forbid a 3rd). Each hop's
// serial content halves; the co-resident WG (OTHER lattice, antidiagonal
// mirror pairing) fills the ~80% idle wait. Occupancy 18.5% -> ~35% is
// the diagnostic signature.
//  - per-wave tile: 32 rows x 64 cols (acc[2][4]); per-wave MFMA/iter
//    unchanged (208) but ds_read chain halved.
//  - W3 B in AGPR (128, asm "+a" pin, v12's proven trick); Win B in VGPR;
//    W1/W2 streamed from L2 (v12 measured ~0.3us/hop for this).
//  - VMEM FIFO per thread IDENTICAL to v15: [out8][up4?][left4?][x2]
//    -> uniform vmcnt(2); bar_vm publish. Choreography carried over.
//  - out payload f16 (v4/v5-validated; absmax unchanged 0.00390625).
//  - ring slots 16KB per (group,cell,k): 2*8192*16KB = 256MB (fits ws).
//
// h handoff per group: pre-swizzled f16 image (16KB) per (cell,k):
//   producer: sc0 sc1 write-through stores -> vmcnt(0)+barrier -> relaxed flag
//   consumer: relaxed flag poll -> global_load_lds
// out = plain nt stores.

typedef _Float16 f16x8 __attribute__((ext_vector_type(8)));
typedef float f32x4 __attribute__((ext_vector_type(4)));
typedef int i32x4 __attribute__((ext_vector_type(4)));

#define OUT_BSTRIDE 2097152   // 16*16*32*256
#define X_BSTRIDE   524288    // 16*16*32*64
#define SLOT_BYTES  16384     // f16 image of one 32x256 h half-tile
#define FLAGS_OFF   1048576
#define RING3_OFF   2097152
#define RING3_BYTES ((size_t)16384 * SLOT_BYTES)   // 2 groups * 8192 slots = 256MB
// persist LDS: P[0,16K) R[16K,32K) L[32K,48K) X[48K,52K)
// fbuf f32[32][260]=33280B overlays [16K,49664) (R,L,X-head; all ordered)
#define SMEM_BYTES  53248
#define SMEM_FB     106496    // fallback kernel layout (unchanged from v15)
#define FB_PITCH    260

__device__ __forceinline__ void bar_raw() {
  asm volatile("" ::: "memory");
  __builtin_amdgcn_s_barrier();
  asm volatile("" ::: "memory");
}
__device__ __forceinline__ void bar_lgkm() {
  asm volatile("s_waitcnt lgkmcnt(0)" ::: "memory");
  __builtin_amdgcn_sched_barrier(0);
  bar_raw();
}
__device__ __forceinline__ void bar_vm() {
  asm volatile("s_waitcnt vmcnt(0)" ::: "memory");
  __builtin_amdgcn_sched_barrier(0);
  bar_raw();
}

// write-through 16B store (MALL-resident, no dirty L2 -> no wbl2 at publish)
__device__ __forceinline__ void store_wt16(void* p, f16x8 v) {
  asm volatile("global_store_dwordx4 %0, %1, off sc0 sc1" :: "v"(p), "v"(v) : "memory");
}

__device__ __forceinline__ void wait_flag(const unsigned int* f) {
  while (__hip_atomic_load(f, __ATOMIC_RELAXED, __HIP_MEMORY_SCOPE_SYSTEM) == 0u)
    __builtin_amdgcn_s_sleep(2);
  asm volatile("" ::: "memory");
}

__device__ __forceinline__ f16x8 conv8f16(const f32x4& a, const f32x4& b) {
  f16x8 r;
  r[0] = (_Float16)a[0]; r[1] = (_Float16)a[1];
  r[2] = (_Float16)a[2]; r[3] = (_Float16)a[3];
  r[4] = (_Float16)b[0]; r[5] = (_Float16)b[1];
  r[6] = (_Float16)b[2]; r[7] = (_Float16)b[3];
  return r;
}

#define GL_AS1(p) ((const __attribute__((address_space(1))) unsigned int*)(p))
#define LDS_AS3(p) ((__attribute__((address_space(3))) unsigned int*)(p))

// async copy of one 16KB f16-image slot into LDS (4 insts/thread, 4 waves)
__device__ __forceinline__ void gll_copy4(const unsigned char* slot, unsigned char* buf,
                                          int w, int lane) {
#pragma unroll
  for (int it = 0; it < 4; ++it) {
    const unsigned char* g = slot + it * 4096 + w * 1024 + lane * 16;
    unsigned char* l = buf + it * 4096 + w * 1024;
    __builtin_amdgcn_global_load_lds(GL_AS1(g), LDS_AS3(l), 16, 0, 0);
  }
}

// ---------------- persistent-path mm (acc[2][4], 32 rows x 64 cols) --------
// Win reg-B (VGPR), KS=64, pitch 128
__device__ __forceinline__ void mmWin(f32x4 (&acc)[2][4], const unsigned char* smem,
                                      const f16x8 (&wb)[2][4],
                                      int l15, int l4, int swz) {
#pragma unroll
  for (int kk = 0; kk < 2; ++kk) {
    const int k0 = kk * 32 + l4 * 8;
    f16x8 ah[2];
#pragma unroll
    for (int mi = 0; mi < 2; ++mi) {
      int byte = (mi * 16 + l15) * 128 + ((k0 * 2) ^ swz);
      ah[mi] = *(const f16x8*)(smem + byte);
    }
#pragma unroll
    for (int mi = 0; mi < 2; ++mi)
#pragma unroll
      for (int ni = 0; ni < 4; ++ni)
        acc[mi][ni] = __builtin_amdgcn_mfma_f32_16x16x32_f16(ah[mi], wb[kk][ni], acc[mi][ni], 0, 0, 0);
  }
}

// W3 AGPR-B over kk range [KK0,KK1), pitch 512
template<int KK0, int KK1>
__device__ __forceinline__ void mmW3(f32x4 (&acc)[2][4], const unsigned char* smem,
                                     const i32x4 (&wa)[8][4],
                                     int l15, int l4, int swz) {
#pragma unroll
  for (int kk = KK0; kk < KK1; ++kk) {
    const int k0 = kk * 32 + l4 * 8;
    f16x8 ah[2];
#pragma unroll
    for (int mi = 0; mi < 2; ++mi) {
      int byte = (mi * 16 + l15) * 512 + ((k0 * 2) ^ swz);
      ah[mi] = *(const f16x8*)(smem + byte);
    }
#pragma unroll
    for (int mi = 0; mi < 2; ++mi)
#pragma unroll
      for (int ni = 0; ni < 4; ++ni) {
        f16x8 b = __builtin_bit_cast(f16x8, wa[kk][ni]);
        acc[mi][ni] = __builtin_amdgcn_mfma_f32_16x16x32_f16(ah[mi], b, acc[mi][ni], 0, 0, 0);
      }
  }
}

// streamed-B (W1/W2 from L2), KS=256, pitch 512
__device__ __forceinline__ void mmS(f32x4 (&acc)[2][4], const unsigned char* smem,
                                    const _Float16* __restrict__ wt,
                                    int ncol0, int l15, int l4, int swz) {
#pragma unroll
  for (int kk = 0; kk < 8; ++kk) {
    const int k0 = kk * 32 + l4 * 8;
    f16x8 ah[2], bh[4];
#pragma unroll
    for (int mi = 0; mi < 2; ++mi) {
      int byte = (mi * 16 + l15) * 512 + ((k0 * 2) ^ swz);
      ah[mi] = *(const f16x8*)(smem + byte);
    }
#pragma unroll
    for (int ni = 0; ni < 4; ++ni) {
      int n = ncol0 + ni * 16 + l15;
      bh[ni] = *(const f16x8*)(wt + n * 256 + k0);
    }
#pragma unroll
    for (int mi = 0; mi < 2; ++mi)
#pragma unroll
      for (int ni = 0; ni < 4; ++ni)
        acc[mi][ni] = __builtin_amdgcn_mfma_f32_16x16x32_f16(ah[mi], bh[ni], acc[mi][ni], 0, 0, 0);
  }
}

// ---------------- fallback-path mm (v15, 512 thr, acc[4][2]) ---------------
template<int KS, int PITCH>
__device__ __forceinline__ void mm1(f32x4 (&acc)[4][2], const unsigned char* smem,
                                    const _Float16* __restrict__ wt,
                                    int ncol0, int l15, int l4, int swz) {
#pragma unroll
  for (int kk = 0; kk < KS / 32; ++kk) {
    const int k0 = kk * 32 + l4 * 8;
    f16x8 ah[4], bh[2];
#pragma unroll
    for (int mi = 0; mi < 4; ++mi) {
      int byte = (mi * 16 + l15) * PITCH + ((k0 * 2) ^ swz);
      ah[mi] = *(const f16x8*)(smem + byte);
    }
#pragma unroll
    for (int ni = 0; ni < 2; ++ni) {
      int n = ncol0 + ni * 16 + l15;
      bh[ni] = *(const f16x8*)(wt + n * KS + k0);
    }
#pragma unroll
    for (int mi = 0; mi < 4; ++mi)
#pragma unroll
      for (int ni = 0; ni < 2; ++ni)
        acc[mi][ni] = __builtin_amdgcn_mfma_f32_16x16x32_f16(ah[mi], bh[ni], acc[mi][ni], 0, 0, 0);
  }
}

// fallback staging: f32 -> f16 swizzled LDS image (512 threads)
template<int BPR, int ITERS, int PITCH>
__device__ __forceinline__ void stage_f16(const float* __restrict__ src, int rstride,
                                          unsigned char* buf, int t) {
#pragma unroll
  for (int it = 0; it < ITERS; ++it) {
    int c = t + it * 512;
    int row = c / BPR, bk = c % BPR;
    const float* p = src + row * rstride + bk * 8;
    f32x4 v0 = *(const f32x4*)p;
    f32x4 v1 = *(const f32x4*)(p + 4);
    f16x8 h8 = conv8f16(v0, v1);
    int byte = row * PITCH + ((bk * 16) ^ ((row & 7) << 4));
    *(f16x8*)(buf + byte) = h8;
  }
}

// ws: bias f32[256]; Win f16[256][64]; W1,W2,W3 f16[256][256] (transposed)
__global__ void mdrnn_prep(const float* __restrict__ W_in, const float* __restrict__ b_in,
                           const float* __restrict__ W_h, const float* __restrict__ b_h,
                           unsigned char* __restrict__ ws) {
  int t = blockIdx.x * 256 + threadIdx.x;
  float* bias = (float*)ws;
  _Float16* win = (_Float16*)(ws + 1024);
  _Float16* wh0 = win + 16384;

  if (t < 256) bias[t] = b_in[t] + b_h[t];
  if (t < 16384)
    __hip_atomic_store((unsigned int*)(ws + FLAGS_OFF) + t, 0u,
                       __ATOMIC_RELAXED, __HIP_MEMORY_SCOPE_SYSTEM);
  if (t < 16384) {
    int n = t >> 6, k = t & 63;
    win[t] = (_Float16)W_in[k * 256 + n];
  }
  if (t < 196608) {
    int m = t >> 16;
    int r = t & 65535;
    int n = r >> 8, k = r & 255;
    (wh0 + m * 65536)[r] = (_Float16)W_h[(m * 256 + k) * 256 + n];
  }
}

__global__ __launch_bounds__(256, 2)
void mdrnn_persist(const float* __restrict__ x, const unsigned char* __restrict__ ws,
                   unsigned char* __restrict__ ring, unsigned int* __restrict__ flags,
                   float* __restrict__ out) {
  const int bx = blockIdx.x;
  const int g = bx & 1;                     // batch group (rows g*32..g*32+31)
  const int raw = bx >> 1;
  const int cell2 = g ? (255 - raw) : raw;  // antidiagonal mirror pairing
  const int i = cell2 >> 4, j = cell2 & 15;

  __shared__ __align__(16) unsigned char smem[SMEM_BYTES];
  unsigned char* P = smem;            // prev-h f16 image 32x256 (persists)
  unsigned char* R = smem + 16384;    // up image
  unsigned char* L = smem + 32768;    // left image
  unsigned char* X = smem + 49152;    // x f16 image 32x64 (4KB)
  float* fbuf = (float*)(smem + 16384);  // overlays R,L,X-head (ordered)

  const int t = threadIdx.x;
  const int lane = t & 63;
  const int w = t >> 6;               // 0..3
  const int l15 = lane & 15, l4 = lane >> 4;
  const int swz = (lane & 7) << 4;
  const int ncol0 = w * 64;           // wave owns 64 output cols

  const float* bias = (const float*)ws;
  const _Float16* win = (const _Float16*)(ws + 1024);
  const _Float16* w1 = win + 16384;
  const _Float16* w2 = w1 + 65536;
  const _Float16* w3 = w2 + 65536;

  const int gcell = (g << 8) + cell2;
  const unsigned int* upF   = flags + (size_t)(gcell - 16) * 32;
  const unsigned int* leftF = flags + (size_t)(gcell - 1) * 32;
  unsigned int* myF = flags + (size_t)gcell * 32;
  const bool has_cons = (i < 15) || (j < 15);

  // ---- hoisted k-invariant B: Win (32 VGPR) ----
  f16x8 wbI[2][4];
#pragma unroll
  for (int kk = 0; kk < 2; ++kk)
#pragma unroll
    for (int ni = 0; ni < 4; ++ni) {
      int n = ncol0 + ni * 16 + l15;
      wbI[kk][ni] = *(const f16x8*)(win + n * 64 + kk * 32 + l4 * 8);
    }
  // ---- AGPR-held W3 B fragments (128 AGPRs/wave, asm-pinned) ----
  i32x4 wa3[8][4];
#pragma unroll
  for (int kk = 0; kk < 8; ++kk)
#pragma unroll
    for (int ni = 0; ni < 4; ++ni) {
      int n = ncol0 + ni * 16 + l15;
      wa3[kk][ni] = __builtin_bit_cast(i32x4, *(const f16x8*)(w3 + n * 256 + kk * 32 + l4 * 8));
    }
#pragma unroll
  for (int kk = 0; kk < 8; ++kk)
#pragma unroll
    for (int ni = 0; ni < 4; ++ni)
      asm volatile("" : "+a"(wa3[kk][ni]));

  // hoisted bias (4 f32)
  float bias4[4];
#pragma unroll
  for (int ni = 0; ni < 4; ++ni) bias4[ni] = bias[ncol0 + ni * 16 + l15];

  // x: thread owns local row t>>3 (0..31), 8 floats at (t&7)*8
  const int xrow = t >> 3, xck = t & 7;
  const float* xbase = x + (size_t)(g * 32 + xrow) * X_BSTRIDE
                         + (size_t)cell2 * 32 * 64 + xck * 8;
  f32x4 xr0 = __builtin_nontemporal_load((const f32x4*)xbase);
  f32x4 xr1 = __builtin_nontemporal_load((const f32x4*)(xbase + 4));

  f16x8 vo16[4];   // deferred out payload (k-1), f16 (static-indexed)

  for (int k = 0; k < 32; ++k) {
    const int cell3 = cell2 * 32 + k;

    // ---- publish x(k) f16 image ----
    {
      f16x8 h8 = conv8f16(xr0, xr1);
      int byte = xrow * 128 + ((xck * 16) ^ ((xrow & 7) << 4));
      *(f16x8*)(X + byte) = h8;
    }
    bar_lgkm();   // X visible; drains prev iter's P-image ds writes

    f32x4 acc[2][4];
#pragma unroll
    for (int mi = 0; mi < 2; ++mi)
#pragma unroll
      for (int ni = 0; ni < 4; ++ni)
        acc[mi][ni] = f32x4{0.f, 0.f, 0.f, 0.f};

    // ---- deferred out stores for k-1 (OLDEST in VMEM FIFO) ----
    if (k > 0) {
      float* oc = out + (size_t)(cell3 - 1) * 256;
#pragma unroll
      for (int it = 0; it < 4; ++it) {
        int c = t + it * 256;
        int row = c >> 5, ck = c & 31;
        f16x8 h = vo16[it];
        f32x4 a{(float)h[0], (float)h[1], (float)h[2], (float)h[3]};
        f32x4 b{(float)h[4], (float)h[5], (float)h[6], (float)h[7]};
        float* op = oc + (size_t)(g * 32 + row) * OUT_BSTRIDE + ck * 8;
        __builtin_nontemporal_store(a, (f32x4*)op);
        __builtin_nontemporal_store(b, (f32x4*)(op + 4));
      }
    }

    // ---- LOCAL phases first (pre-arrival work) ----
    mmWin(acc, X, wbI, l15, l4, swz);
    if (k > 0) mmW3<0, 4>(acc, P, wa3, l15, l4, swz);   // W3 1st half

    // ---- poll, then remote fetches + x prefetch ----
    if (i > 0 && t == 0)  wait_flag(upF + k);
    if (j > 0 && t == 64) wait_flag(leftF + k);
    bar_raw();
    __builtin_amdgcn_sched_barrier(0);
    if (i > 0) gll_copy4(ring + (size_t)((gcell - 16) * 32 + k) * SLOT_BYTES, R, w, lane);
    if (j > 0) gll_copy4(ring + (size_t)((gcell - 1) * 32 + k) * SLOT_BYTES, L, w, lane);
    {
      int kn = (k < 31) ? k + 1 : 31;
      xr0 = __builtin_nontemporal_load((const f32x4*)(xbase + kn * 64));
      xr1 = __builtin_nontemporal_load((const f32x4*)(xbase + kn * 64 + 4));
    }
    __builtin_amdgcn_sched_barrier(0);

    // ---- W3 2nd half: local work covering the remote fetch latency ----
    if (k > 0) mmW3<4, 8>(acc, P, wa3, l15, l4, swz);

    // per-thread VMEM FIFO: [out8?][up4?][left4?][x2] -> uniform vmcnt(2)
    if (i > 0 || j > 0) {
      asm volatile("s_waitcnt vmcnt(2)" ::: "memory");
      __builtin_amdgcn_sched_barrier(0);
      bar_raw();   // all waves' fetched portions in LDS
      if (i > 0) mmS(acc, R, w1, ncol0, l15, l4, swz);
      if (j > 0) mmS(acc, L, w2, ncol0, l15, l4, swz);
    }

    // ---- tanh in-place (register-only) ----
#pragma unroll
    for (int mi = 0; mi < 2; ++mi)
#pragma unroll
      for (int ni = 0; ni < 4; ++ni) {
        float bv = bias4[ni];
#pragma unroll
        for (int r = 0; r < 4; ++r) {
          float v = acc[mi][ni][r] + bv;
          float e = __expf(2.f * v);
          acc[mi][ni][r] = 1.f - 2.f / (e + 1.f);
        }
      }

    // ---- epilogue: fbuf transpose (fbuf overlays R/L/X-head) ----
    bar_raw();   // all waves done reading P/R/L/X
#pragma unroll
    for (int mi = 0; mi < 2; ++mi)
#pragma unroll
      for (int ni = 0; ni < 4; ++ni) {
        int col = ncol0 + ni * 16 + l15;
#pragma unroll
        for (int r = 0; r < 4; ++r) {
          int row = mi * 16 + l4 * 4 + r;
          fbuf[row * FB_PITCH + col] = acc[mi][ni][r];
        }
      }
    bar_lgkm();

    // ---- fbuf -> P image + ring wt stores; hold f16 payload for out ----
    unsigned char* slotW = ring + (size_t)(gcell * 32 + k) * SLOT_BYTES;
#pragma unroll
    for (int it = 0; it < 4; ++it) {
      int c = t + it * 256;
      int row = c >> 5, ck = c & 31;
      const float* p = fbuf + row * FB_PITCH + ck * 8;
      f32x4 v0 = *(const f32x4*)p;
      f32x4 v1 = *(const f32x4*)(p + 4);
      f16x8 h8 = conv8f16(v0, v1);
      vo16[it] = h8;
      int byte = row * 512 + ((ck * 16) ^ ((row & 7) << 4));
      *(f16x8*)(P + byte) = h8;
      if (has_cons) store_wt16(slotW + byte, h8);
    }

    // ---- publish: drain ring stores, then relaxed flag ----
    bar_vm();
    if (has_cons && t == 0)
      __hip_atomic_store(myF + k, 1u, __ATOMIC_RELAXED, __HIP_MEMORY_SCOPE_SYSTEM);
  }

  // ---- final deferred out stores (k = 31) ----
  {
    float* oc = out + (size_t)(cell2 * 32 + 31) * 256;
#pragma unroll
    for (int it = 0; it < 4; ++it) {
      int c = t + it * 256;
      int row = c >> 5, ck = c & 31;
      f16x8 h = vo16[it];
      f32x4 a{(float)h[0], (float)h[1], (float)h[2], (float)h[3]};
      f32x4 b{(float)h[4], (float)h[5], (float)h[6], (float)h[7]};
      float* op = oc + (size_t)(g * 32 + row) * OUT_BSTRIDE + ck * 8;
      __builtin_nontemporal_store(a, (f32x4*)op);
      __builtin_nontemporal_store(b, (f32x4*)(op + 4));
    }
  }
}

// ================= fallback (dispatch-per-wavefront, f16, 512 thr) =========
__global__ __launch_bounds__(512)
void mdrnn_cell2(int s, const float* __restrict__ x, const unsigned char* __restrict__ ws,
                 float* __restrict__ out) {
  const int bx = blockIdx.x;
  const int i = bx >> 4, j = bx & 15;
  const int kc = s - i - j;
  if (kc < 0 || kc >= 32) return;

  __shared__ __align__(16) unsigned char smem[SMEM_FB];
  const int t = threadIdx.x;
  const int lane = t & 63;
  const int w = t >> 6;
  const int l15 = lane & 15, l4 = lane >> 4;
  const int swz = (lane & 7) << 4;
  const int ncol0 = w * 32;
  unsigned char* ABUF = smem;            // 32KB f16 image
  unsigned char* XBUF = smem + 32768;    // 8KB f16 image
  float* fbuf = (float*)smem;            // overlays ABUF/XBUF after stages

  const float* bias = (const float*)ws;
  const _Float16* win = (const _Float16*)(ws + 1024);
  const _Float16* w1 = win + 16384;
  const _Float16* w2 = w1 + 65536;
  const _Float16* w3 = w2 + 65536;

  const int cell3 = (i * 16 + j) * 32 + kc;

  f32x4 acc[4][2];
#pragma unroll
  for (int mi = 0; mi < 4; ++mi)
#pragma unroll
    for (int ni = 0; ni < 2; ++ni)
      acc[mi][ni] = f32x4{0.f, 0.f, 0.f, 0.f};

  stage_f16<8, 1, 128>(x + (size_t)cell3 * 64, X_BSTRIDE, XBUF, t);
  bar_lgkm();
  mm1<64, 128>(acc, XBUF, win, ncol0, l15, l4, swz);

  if (j > 0) {
    bar_raw();
    stage_f16<32, 4, 512>(out + (size_t)(cell3 - 32) * 256, OUT_BSTRIDE, ABUF, t);
    bar_lgkm();
    mm1<256, 512>(acc, ABUF, w2, ncol0, l15, l4, swz);
  }
  if (i > 0) {
    bar_raw();
    stage_f16<32, 4, 512>(out + (size_t)(cell3 - 512) * 256, OUT_BSTRIDE, ABUF, t);
    bar_lgkm();
    mm1<256, 512>(acc, ABUF, w1, ncol0, l15, l4, swz);
  }
  if (kc > 0) {
    bar_raw();
    stage_f16<32, 4, 512>(out + (size_t)(cell3 - 1) * 256, OUT_BSTRIDE, ABUF, t);
    bar_lgkm();
    mm1<256, 512>(acc, ABUF, w3, ncol0, l15, l4, swz);
  }

  bar_raw();
#pragma unroll
  for (int mi = 0; mi < 4; ++mi)
#pragma unroll
    for (int ni = 0; ni < 2; ++ni) {
      int col = ncol0 + ni * 16 + l15;
      float bv = bias[col];
#pragma unroll
      for (int r = 0; r < 4; ++r) {
        int row = mi * 16 + l4 * 4 + r;
        float v = acc[mi][ni][r] + bv;
        float e = __expf(2.f * v);
        fbuf[row * FB_PITCH + col] = 1.f - 2.f / (e + 1.f);
      }
    }
  bar_lgkm();
#pragma unroll
  for (int it = 0; it < 4; ++it) {
    int c = t + it * 512;
    int row = c >> 5, ck = c & 31;
    const float* p = fbuf + row * FB_PITCH + ck * 8;
    f32x4 v0 = *(const f32x4*)p;
    f32x4 v1 = *(const f32x4*)(p + 4);
    float* op = out + (size_t)row * OUT_BSTRIDE + (size_t)cell3 * 256 + ck * 8;
    *(f32x4*)op = v0;
    *(f32x4*)(op + 4) = v1;
  }
}

extern "C" void kernel_launch(void* const* d_in, const int* in_sizes, int n_in,
                              void* d_out, int out_size, void* d_ws, size_t ws_size,
                              hipStream_t stream) {
  const float* x    = (const float*)d_in[0];
  const float* W_in = (const float*)d_in[1];
  const float* b_in = (const float*)d_in[2];
  const float* W_h  = (const float*)d_in[3];
  const float* b_h  = (const float*)d_in[4];
  float* out = (float*)d_out;
  unsigned char* ws = (unsigned char*)d_ws;

  mdrnn_prep<<<768, 256, 0, stream>>>(W_in, b_in, W_h, b_h, ws);

  if (ws_size >= (size_t)RING3_OFF + RING3_BYTES) {
    mdrnn_persist<<<512, 256, 0, stream>>>(x, ws, ws + RING3_OFF,
                                           (unsigned int*)(ws + FLAGS_OFF), out);
  } else {
    for (int s = 0; s <= 61; ++s)
      mdrnn_cell2<<<256, 512, 0, stream>>>(s, x, ws, out);
  }
}

// Round 16
// 870.232 us; speedup vs baseline: 1.7263x; 1.7263x over previous
//
#include <hip/hip_runtime.h>

// MD-RNN on MI355X. B=64, Hd=16, Wd=16, Cd=32, D=64, HID=256.
// hidden[i][j][k] = tanh(x@W_in + up@W1 + left@W2 + prev@W3 + bias)
// Persistent dataflow: 256 WGs (one per (i,j), 1/CU), each scans k=0..31.
//
// v17 = EXACT v15/v12 restoration (873.8us, session best, reproduced 2x).
// v16's batch-split measured 1502us (mirror-paired co-resident WG spins
// until the first lattice drains -> lattices serialize; hop cost is
// latency-dominated so half-work hops are NOT half-time). Every structural
// departure (v4 tile, v6 4-wave, v9 VGPR-preload, v13 X-dbuf, v16 split)
// and every micro-tweak (v14 s_sleep/bias-fold) measured worse or null.
// This config is the measured optimum:
//  - f16 single-term MFMA, 8 waves x (64rows x 32cols)
//  - AGPR-held W1/W2 B-fragments (asm "+a" pin: the only reg-hold the
//    512-thread allocator cannot rematerialize; 128 AGPRs + 128 VGPRs
//    = the full 2-wave/SIMD unified budget)
//  - VGPR-held Win/W3 B (small enough to survive)
//  - W3 split around the gll fetch (remote latency covered by local work)
//  - merged W1+W2 phase behind one uniform vmcnt(2) + single barrier
//  - deferred out stores (held in regs, issued next iter pre-poll, oldest
//    in VMEM FIFO -> counted-vmcnt constants stay valid)
//  - 2-lane flag poll (s_sleep(2)), write-through ring publish
//
// h handoff: pre-swizzled f16 image (32KB) per (i,j,k), unique slot:
//   producer: sc0 sc1 write-through stores -> vmcnt(0)+barrier -> relaxed flag
//   consumer: relaxed flag poll -> global_load_lds (up is same-XCD)
// out = plain nt stores.

typedef _Float16 f16x8 __attribute__((ext_vector_type(8)));
typedef float f32x4 __attribute__((ext_vector_type(4)));
typedef int i32x4 __attribute__((ext_vector_type(4)));

#define OUT_BSTRIDE 2097152   // 16*16*32*256
#define X_BSTRIDE   524288    // 16*16*32*64
#define SLOT_BYTES  32768     // f16 image of one 64x256 h tile
#define FLAGS_OFF   1048576
#define RING3_OFF   2097152
#define RING3_BYTES ((size_t)8192 * SLOT_BYTES)   // 256MB
// LDS: P[0,32K) R[32K,64K) L[64K,96K) X[96K,104K); fbuf overlays [32K,99.3K)
#define SMEM_BYTES  106496
#define FB_PITCH    260

__device__ __forceinline__ void bar_raw() {
  asm volatile("" ::: "memory");
  __builtin_amdgcn_s_barrier();
  asm volatile("" ::: "memory");
}
__device__ __forceinline__ void bar_lgkm() {
  asm volatile("s_waitcnt lgkmcnt(0)" ::: "memory");
  __builtin_amdgcn_sched_barrier(0);
  bar_raw();
}
__device__ __forceinline__ void bar_vm() {
  asm volatile("s_waitcnt vmcnt(0)" ::: "memory");
  __builtin_amdgcn_sched_barrier(0);
  bar_raw();
}

// write-through 16B store (MALL-resident, no dirty L2 -> no wbl2 at publish)
__device__ __forceinline__ void store_wt16(void* p, f16x8 v) {
  asm volatile("global_store_dwordx4 %0, %1, off sc0 sc1" :: "v"(p), "v"(v) : "memory");
}

__device__ __forceinline__ void wait_flag(const unsigned int* f) {
  while (__hip_atomic_load(f, __ATOMIC_RELAXED, __HIP_MEMORY_SCOPE_SYSTEM) == 0u)
    __builtin_amdgcn_s_sleep(2);
  asm volatile("" ::: "memory");
}

__device__ __forceinline__ f16x8 conv8f16(const f32x4& a, const f32x4& b) {
  f16x8 r;
  r[0] = (_Float16)a[0]; r[1] = (_Float16)a[1];
  r[2] = (_Float16)a[2]; r[3] = (_Float16)a[3];
  r[4] = (_Float16)b[0]; r[5] = (_Float16)b[1];
  r[6] = (_Float16)b[2]; r[7] = (_Float16)b[3];
  return r;
}

#define GL_AS1(p) ((const __attribute__((address_space(1))) unsigned int*)(p))
#define LDS_AS3(p) ((__attribute__((address_space(3))) unsigned int*)(p))

// async copy of one 32KB f16-image slot into LDS (4 insts/wave, 8 waves)
__device__ __forceinline__ void gll_copy4(const unsigned char* slot, unsigned char* buf,
                                          int w, int lane) {
#pragma unroll
  for (int it = 0; it < 4; ++it) {
    const unsigned char* g = slot + it * 8192 + w * 1024 + lane * 16;
    unsigned char* l = buf + it * 8192 + w * 1024;
    __builtin_amdgcn_global_load_lds(GL_AS1(g), LDS_AS3(l), 16, 0, 0);
  }
}

// streamed-B f16 (fallback path): acc += A*B
template<int KS, int PITCH>
__device__ __forceinline__ void mm1(f32x4 (&acc)[4][2], const unsigned char* smem,
                                    const _Float16* __restrict__ wt,
                                    int ncol0, int l15, int l4, int swz) {
#pragma unroll
  for (int kk = 0; kk < KS / 32; ++kk) {
    const int k0 = kk * 32 + l4 * 8;
    f16x8 ah[4], bh[2];
#pragma unroll
    for (int mi = 0; mi < 4; ++mi) {
      int byte = (mi * 16 + l15) * PITCH + ((k0 * 2) ^ swz);
      ah[mi] = *(const f16x8*)(smem + byte);
    }
#pragma unroll
    for (int ni = 0; ni < 2; ++ni) {
      int n = ncol0 + ni * 16 + l15;
      bh[ni] = *(const f16x8*)(wt + n * KS + k0);
    }
#pragma unroll
    for (int mi = 0; mi < 4; ++mi)
#pragma unroll
      for (int ni = 0; ni < 2; ++ni)
        acc[mi][ni] = __builtin_amdgcn_mfma_f32_16x16x32_f16(ah[mi], bh[ni], acc[mi][ni], 0, 0, 0);
  }
}

// reg-B f16 over kk range [KK0,KK1): B fragments preloaded (VGPR holds)
template<int PITCH, int KK0, int KK1, int NB>
__device__ __forceinline__ void mm1r_rng(f32x4 (&acc)[4][2], const unsigned char* smem,
                                         const f16x8 (&bh)[NB][2],
                                         int l15, int l4, int swz) {
#pragma unroll
  for (int kk = KK0; kk < KK1; ++kk) {
    const int k0 = kk * 32 + l4 * 8;
    f16x8 ah[4];
#pragma unroll
    for (int mi = 0; mi < 4; ++mi) {
      int byte = (mi * 16 + l15) * PITCH + ((k0 * 2) ^ swz);
      ah[mi] = *(const f16x8*)(smem + byte);
    }
#pragma unroll
    for (int mi = 0; mi < 4; ++mi)
#pragma unroll
      for (int ni = 0; ni < 2; ++ni)
        acc[mi][ni] = __builtin_amdgcn_mfma_f32_16x16x32_f16(ah[mi], bh[kk][ni], acc[mi][ni], 0, 0, 0);
  }
}

// AGPR-held-B f16, KS=256: B fragments live in AGPRs (bitcast at use)
__device__ __forceinline__ void mm1a(f32x4 (&acc)[4][2], const unsigned char* smem,
                                     const i32x4 (&wb)[8][2],
                                     int l15, int l4, int swz) {
#pragma unroll
  for (int kk = 0; kk < 8; ++kk) {
    const int k0 = kk * 32 + l4 * 8;
    f16x8 ah[4];
#pragma unroll
    for (int mi = 0; mi < 4; ++mi) {
      int byte = (mi * 16 + l15) * 512 + ((k0 * 2) ^ swz);
      ah[mi] = *(const f16x8*)(smem + byte);
    }
#pragma unroll
    for (int mi = 0; mi < 4; ++mi)
#pragma unroll
      for (int ni = 0; ni < 2; ++ni) {
        f16x8 b = __builtin_bit_cast(f16x8, wb[kk][ni]);
        acc[mi][ni] = __builtin_amdgcn_mfma_f32_16x16x32_f16(ah[mi], b, acc[mi][ni], 0, 0, 0);
      }
  }
}

// fallback staging: f32 -> f16 swizzled LDS image
template<int BPR, int ITERS, int PITCH>
__device__ __forceinline__ void stage_f16(const float* __restrict__ src, int rstride,
                                          unsigned char* buf, int t) {
#pragma unroll
  for (int it = 0; it < ITERS; ++it) {
    int c = t + it * 512;
    int row = c / BPR, bk = c % BPR;
    const float* p = src + row * rstride + bk * 8;
    f32x4 v0 = *(const f32x4*)p;
    f32x4 v1 = *(const f32x4*)(p + 4);
    f16x8 h8 = conv8f16(v0, v1);
    int byte = row * PITCH + ((bk * 16) ^ ((row & 7) << 4));
    *(f16x8*)(buf + byte) = h8;
  }
}

// ws: bias f32[256]; Win f16[256][64]; W1,W2,W3 f16[256][256] (transposed)
__global__ void mdrnn_prep(const float* __restrict__ W_in, const float* __restrict__ b_in,
                           const float* __restrict__ W_h, const float* __restrict__ b_h,
                           unsigned char* __restrict__ ws) {
  int t = blockIdx.x * 256 + threadIdx.x;
  float* bias = (float*)ws;
  _Float16* win = (_Float16*)(ws + 1024);
  _Float16* wh0 = win + 16384;

  if (t < 256) bias[t] = b_in[t] + b_h[t];
  if (t < 8192)
    __hip_atomic_store((unsigned int*)(ws + FLAGS_OFF) + t, 0u,
                       __ATOMIC_RELAXED, __HIP_MEMORY_SCOPE_SYSTEM);
  if (t < 16384) {
    int n = t >> 6, k = t & 63;
    win[t] = (_Float16)W_in[k * 256 + n];
  }
  if (t < 196608) {
    int m = t >> 16;
    int r = t & 65535;
    int n = r >> 8, k = r & 255;
    (wh0 + m * 65536)[r] = (_Float16)W_h[(m * 256 + k) * 256 + n];
  }
}

__global__ __launch_bounds__(512, 2)
void mdrnn_persist(const float* __restrict__ x, const unsigned char* __restrict__ ws,
                   unsigned char* __restrict__ ring, unsigned int* __restrict__ flags,
                   float* __restrict__ out) {
  const int bx = blockIdx.x;
  const int i = bx >> 4, j = bx & 15;

  __shared__ __align__(16) unsigned char smem[SMEM_BYTES];
  unsigned char* P = smem;            // prev-h f16 image (persists across k)
  unsigned char* R = smem + 32768;    // up image
  unsigned char* L = smem + 65536;    // left image
  unsigned char* X = smem + 98304;    // x f16 image (8KB)
  float* fbuf = (float*)(smem + 32768);  // overlays R,L,X tail (all consumed)

  const int t = threadIdx.x;
  const int lane = t & 63;
  const int w = t >> 6;
  const int l15 = lane & 15, l4 = lane >> 4;
  const int swz = (lane & 7) << 4;
  const int ncol0 = w * 32;

  const float* bias = (const float*)ws;
  const _Float16* win = (const _Float16*)(ws + 1024);
  const _Float16* w1 = win + 16384;
  const _Float16* w2 = w1 + 65536;
  const _Float16* w3 = w2 + 65536;

  const int cell2 = bx;
  const unsigned int* upF   = flags + (size_t)(cell2 - 16) * 32;
  const unsigned int* leftF = flags + (size_t)(cell2 - 1) * 32;
  unsigned int* myF = flags + (size_t)cell2 * 32;
  const bool has_cons = (i < 15) || (j < 15);

  // ---- hoisted k-invariant B fragments: Win (16 VGPR) + W3 (64 VGPR) ----
  f16x8 wbI[2][2], wb3[8][2];
#pragma unroll
  for (int kk = 0; kk < 2; ++kk)
#pragma unroll
    for (int ni = 0; ni < 2; ++ni) {
      int n = ncol0 + ni * 16 + l15;
      wbI[kk][ni] = *(const f16x8*)(win + n * 64 + kk * 32 + l4 * 8);
    }
#pragma unroll
  for (int kk = 0; kk < 8; ++kk)
#pragma unroll
    for (int ni = 0; ni < 2; ++ni) {
      int n = ncol0 + ni * 16 + l15;
      wb3[kk][ni] = *(const f16x8*)(w3 + n * 256 + kk * 32 + l4 * 8);
    }

  // ---- AGPR-held W1/W2 B fragments (64+64 = 128 AGPRs/wave) ----
  i32x4 wa1[8][2], wa2[8][2];
#pragma unroll
  for (int kk = 0; kk < 8; ++kk)
#pragma unroll
    for (int ni = 0; ni < 2; ++ni) {
      int n = ncol0 + ni * 16 + l15;
      wa1[kk][ni] = __builtin_bit_cast(i32x4, *(const f16x8*)(w1 + n * 256 + kk * 32 + l4 * 8));
      wa2[kk][ni] = __builtin_bit_cast(i32x4, *(const f16x8*)(w2 + n * 256 + kk * 32 + l4 * 8));
    }
  // pin into AGPR class; asm-defined values cannot be rematerialized
#pragma unroll
  for (int kk = 0; kk < 8; ++kk)
#pragma unroll
    for (int ni = 0; ni < 2; ++ni) {
      asm volatile("" : "+a"(wa1[kk][ni]));
      asm volatile("" : "+a"(wa2[kk][ni]));
    }

  // hoisted bias (2 f32)
  float bias2[2];
#pragma unroll
  for (int ni = 0; ni < 2; ++ni) bias2[ni] = bias[ncol0 + ni * 16 + l15];

  const int xrow = t >> 3, xck = t & 7;
  const float* xbase = x + (size_t)xrow * X_BSTRIDE + (size_t)cell2 * 32 * 64 + xck * 8;
  f32x4 xr0 = __builtin_nontemporal_load((const f32x4*)xbase);
  f32x4 xr1 = __builtin_nontemporal_load((const f32x4*)(xbase + 4));

  f32x4 vo0[4], vo1[4];   // deferred out-store payload (k-1), static-indexed

  for (int k = 0; k < 32; ++k) {
    const int cell3 = cell2 * 32 + k;

    // ---- publish x(k) f16 image ----
    {
      f16x8 h8 = conv8f16(xr0, xr1);
      int byte = xrow * 128 + ((xck * 16) ^ ((xrow & 7) << 4));
      *(f16x8*)(X + byte) = h8;
    }
    bar_lgkm();   // X visible to all; also drains prev iter's P-image ds writes

    f32x4 acc[4][2];
#pragma unroll
    for (int mi = 0; mi < 4; ++mi)
#pragma unroll
      for (int ni = 0; ni < 2; ++ni)
        acc[mi][ni] = f32x4{0.f, 0.f, 0.f, 0.f};

    // ---- deferred out stores for k-1 (earliest: OLDEST in VMEM FIFO,
    //      acks drain under Win+W3, off the publish chain) ----
    if (k > 0) {
      float* oc = out + (size_t)(cell3 - 1) * 256;
#pragma unroll
      for (int it = 0; it < 4; ++it) {
        int c = t + it * 512;
        int row = c >> 5, ck = c & 31;
        float* op = oc + (size_t)row * OUT_BSTRIDE + ck * 8;
        __builtin_nontemporal_store(vo0[it], (f32x4*)op);
        __builtin_nontemporal_store(vo1[it], (f32x4*)(op + 4));
      }
    }

    // ---- LOCAL phases first (pre-arrival work, off the inter-WG path) ----
    mm1r_rng<128, 0, 2, 2>(acc, X, wbI, l15, l4, swz);        // Win (full)
    if (k > 0) mm1r_rng<512, 0, 4, 8>(acc, P, wb3, l15, l4, swz);  // W3 1st half

    // ---- poll (post-arrival segment starts here), then fetches ----
    if (i > 0 && t == 0)  wait_flag(upF + k);
    if (j > 0 && t == 64) wait_flag(leftF + k);
    bar_raw();
    __builtin_amdgcn_sched_barrier(0);
    if (i > 0) gll_copy4(ring + (size_t)((cell2 - 16) * 32 + k) * SLOT_BYTES, R, w, lane);
    if (j > 0) gll_copy4(ring + (size_t)((cell2 - 1) * 32 + k) * SLOT_BYTES, L, w, lane);
    {
      int kn = (k < 31) ? k + 1 : 31;
      xr0 = __builtin_nontemporal_load((const f32x4*)(xbase + kn * 64));
      xr1 = __builtin_nontemporal_load((const f32x4*)(xbase + kn * 64 + 4));
    }
    __builtin_amdgcn_sched_barrier(0);

    // ---- W3 2nd half: local work covering the remote fetch latency ----
    if (k > 0) mm1r_rng<512, 4, 8, 8>(acc, P, wb3, l15, l4, swz);

    // per-thread VMEM FIFO: [out8][up4?][left4?][x2] -> uniform vmcnt(2)
    if (i > 0 || j > 0) {
      asm volatile("s_waitcnt vmcnt(2)" ::: "memory");
      __builtin_amdgcn_sched_barrier(0);
      bar_raw();   // all waves' fetched portions in LDS
      if (i > 0) mm1a(acc, R, wa1, l15, l4, swz);   // pure LDS+MFMA (B in AGPR)
      if (j > 0) mm1a(acc, L, wa2, l15, l4, swz);
    }

    // ---- tanh in-place (register-only, before the barrier) ----
#pragma unroll
    for (int mi = 0; mi < 4; ++mi)
#pragma unroll
      for (int ni = 0; ni < 2; ++ni) {
        float bv = bias2[ni];
#pragma unroll
        for (int r = 0; r < 4; ++r) {
          float v = acc[mi][ni][r] + bv;
          float e = __expf(2.f * v);
          acc[mi][ni][r] = 1.f - 2.f / (e + 1.f);
        }
      }

    // ---- epilogue: fbuf transpose (after barrier: fbuf overlays R/L/X) ----
    bar_raw();   // all waves done reading P/R/L/X
#pragma unroll
    for (int mi = 0; mi < 4; ++mi)
#pragma unroll
      for (int ni = 0; ni < 2; ++ni) {
        int col = ncol0 + ni * 16 + l15;
#pragma unroll
        for (int r = 0; r < 4; ++r) {
          int row = mi * 16 + l4 * 4 + r;
          fbuf[row * FB_PITCH + col] = acc[mi][ni][r];
        }
      }
    bar_lgkm();

    // ---- fbuf -> P image + ring wt stores; hold f32 payload for out ----
    unsigned char* slotW = ring + (size_t)cell3 * SLOT_BYTES;
#pragma unroll
    for (int it = 0; it < 4; ++it) {
      int c = t + it * 512;
      int row = c >> 5, ck = c & 31;
      const float* p = fbuf + row * FB_PITCH + ck * 8;
      f32x4 v0 = *(const f32x4*)p;
      f32x4 v1 = *(const f32x4*)(p + 4);
      vo0[it] = v0;
      vo1[it] = v1;
      f16x8 h8 = conv8f16(v0, v1);
      int byte = row * 512 + ((ck * 16) ^ ((row & 7) << 4));
      *(f16x8*)(P + byte) = h8;
      if (has_cons) store_wt16(slotW + byte, h8);
    }

    // ---- publish: drain ring stores, then relaxed flag ----
    bar_vm();
    if (has_cons && t == 0)
      __hip_atomic_store(myF + k, 1u, __ATOMIC_RELAXED, __HIP_MEMORY_SCOPE_SYSTEM);
  }

  // ---- final deferred out stores (k = 31) ----
  {
    float* oc = out + (size_t)(cell2 * 32 + 31) * 256;
#pragma unroll
    for (int it = 0; it < 4; ++it) {
      int c = t + it * 512;
      int row = c >> 5, ck = c & 31;
      float* op = oc + (size_t)row * OUT_BSTRIDE + ck * 8;
      __builtin_nontemporal_store(vo0[it], (f32x4*)op);
      __builtin_nontemporal_store(vo1[it], (f32x4*)(op + 4));
    }
  }
}

// ================= fallback (dispatch-per-wavefront, f16) =================
__global__ __launch_bounds__(512)
void mdrnn_cell2(int s, const float* __restrict__ x, const unsigned char* __restrict__ ws,
                 float* __restrict__ out) {
  const int bx = blockIdx.x;
  const int i = bx >> 4, j = bx & 15;
  const int kc = s - i - j;
  if (kc < 0 || kc >= 32) return;

  __shared__ __align__(16) unsigned char smem[SMEM_BYTES];
  const int t = threadIdx.x;
  const int lane = t & 63;
  const int w = t >> 6;
  const int l15 = lane & 15, l4 = lane >> 4;
  const int swz = (lane & 7) << 4;
  const int ncol0 = w * 32;
  unsigned char* ABUF = smem;            // 32KB f16 image
  unsigned char* XBUF = smem + 32768;    // 8KB f16 image
  float* fbuf = (float*)smem;            // overlays ABUF/XBUF after stages

  const float* bias = (const float*)ws;
  const _Float16* win = (const _Float16*)(ws + 1024);
  const _Float16* w1 = win + 16384;
  const _Float16* w2 = w1 + 65536;
  const _Float16* w3 = w2 + 65536;

  const int cell3 = (i * 16 + j) * 32 + kc;

  f32x4 acc[4][2];
#pragma unroll
  for (int mi = 0; mi < 4; ++mi)
#pragma unroll
    for (int ni = 0; ni < 2; ++ni)
      acc[mi][ni] = f32x4{0.f, 0.f, 0.f, 0.f};

  stage_f16<8, 1, 128>(x + (size_t)cell3 * 64, X_BSTRIDE, XBUF, t);
  bar_lgkm();
  mm1<64, 128>(acc, XBUF, win, ncol0, l15, l4, swz);

  if (j > 0) {
    bar_raw();
    stage_f16<32, 4, 512>(out + (size_t)(cell3 - 32) * 256, OUT_BSTRIDE, ABUF, t);
    bar_lgkm();
    mm1<256, 512>(acc, ABUF, w2, ncol0, l15, l4, swz);
  }
  if (i > 0) {
    bar_raw();
    stage_f16<32, 4, 512>(out + (size_t)(cell3 - 512) * 256, OUT_BSTRIDE, ABUF, t);
    bar_lgkm();
    mm1<256, 512>(acc, ABUF, w1, ncol0, l15, l4, swz);
  }
  if (kc > 0) {
    bar_raw();
    stage_f16<32, 4, 512>(out + (size_t)(cell3 - 1) * 256, OUT_BSTRIDE, ABUF, t);
    bar_lgkm();
    mm1<256, 512>(acc, ABUF, w3, ncol0, l15, l4, swz);
  }

  bar_raw();
#pragma unroll
  for (int mi = 0; mi < 4; ++mi)
#pragma unroll
    for (int ni = 0; ni < 2; ++ni) {
      int col = ncol0 + ni * 16 + l15;
      float bv = bias[col];
#pragma unroll
      for (int r = 0; r < 4; ++r) {
        int row = mi * 16 + l4 * 4 + r;
        float v = acc[mi][ni][r] + bv;
        float e = __expf(2.f * v);
        fbuf[row * FB_PITCH + col] = 1.f - 2.f / (e + 1.f);
      }
    }
  bar_lgkm();
#pragma unroll
  for (int it = 0; it < 4; ++it) {
    int c = t + it * 512;
    int row = c >> 5, ck = c & 31;
    const float* p = fbuf + row * FB_PITCH + ck * 8;
    f32x4 v0 = *(const f32x4*)p;
    f32x4 v1 = *(const f32x4*)(p + 4);
    float* op = out + (size_t)row * OUT_BSTRIDE + (size_t)cell3 * 256 + ck * 8;
    *(f32x4*)op = v0;
    *(f32x4*)(op + 4) = v1;
  }
}

extern "C" void kernel_launch(void* const* d_in, const int* in_sizes, int n_in,
                              void* d_out, int out_size, void* d_ws, size_t ws_size,
                              hipStream_t stream) {
  const float* x    = (const float*)d_in[0];
  const float* W_in = (const float*)d_in[1];
  const float* b_in = (const float*)d_in[2];
  const float* W_h  = (const float*)d_in[3];
  const float* b_h  = (const float*)d_in[4];
  float* out = (float*)d_out;
  unsigned char* ws = (unsigned char*)d_ws;

  mdrnn_prep<<<768, 256, 0, stream>>>(W_in, b_in, W_h, b_h, ws);

  if (ws_size >= (size_t)RING3_OFF + RING3_BYTES) {
    mdrnn_persist<<<256, 512, 0, stream>>>(x, ws, ws + RING3_OFF,
                                           (unsigned int*)(ws + FLAGS_OFF), out);
  } else {
    for (int s = 0; s <= 61; ++s)
      mdrnn_cell2<<<256, 512, 0, stream>>>(s, x, ws, out);
  }
}